// Round 1
// baseline (775.523 us; speedup 1.0000x reference)
//
#include <hip/hip_runtime.h>

// DepthDeformConvPack on MI355X — round 1: correct fp32 implementation.
// Stage 1: offset = conv3x3(cat(x,depth); off_w, off_b)            [4,18,64,64]
// Stage 2: mask = sigmoid(deform_conv(depth, offset; mask_w,b))    [4,9,64,64]
// Stage 3: out = modulated_deform_conv(x, offset, mask; weight,b)  [4,256,64,64]
//
// Constants for this problem: N=4, CIN=256, DC=64, COUT=256, H=W=Ho=Wo=64,
// K=3x3=9, stride=1, pad=1, dil=1, groups=1, DG=1.

#define HW 4096

// ---------------------------------------------------------------------------
// K1: offset conv. grid=(4*64) blocks (n,ho), 256 threads = 4 waves x 64 lanes.
// lane = wo. Wave w handles input channels [80w, 80w+80). 18 accumulators.
// Horizontal taps via __shfl within the wave; weights via uniform scalar loads.
// ---------------------------------------------------------------------------
__global__ __launch_bounds__(256) void k_offset_conv(
    const float* __restrict__ x, const float* __restrict__ depth,
    const float* __restrict__ off_w, const float* __restrict__ off_b,
    float* __restrict__ offs)
{
  const int n  = blockIdx.x >> 6;
  const int ho = blockIdx.x & 63;
  const int tid  = threadIdx.x;
  const int lane = tid & 63;          // == wo
  const int wave = tid >> 6;

  float acc[18];
#pragma unroll
  for (int i = 0; i < 18; ++i) acc[i] = 0.f;

  // force wave-uniform scalar base so weight addresses become s_loads
  const int c0 = __builtin_amdgcn_readfirstlane(wave * 80);

  for (int ci = 0; ci < 80; ++ci) {
    const int c = c0 + ci;
    const float* p = (c < 256) ? (x + (((n << 8) + c) << 12))
                               : (depth + (((n << 6) + (c - 256)) << 12));
    const float v0 = (ho > 0)  ? p[((ho - 1) << 6) + lane] : 0.f;
    const float v1 =             p[( ho      << 6) + lane];
    const float v2 = (ho < 63) ? p[((ho + 1) << 6) + lane] : 0.f;

    float v[9];
#pragma unroll
    for (int ky = 0; ky < 3; ++ky) {
      const float r = (ky == 0) ? v0 : ((ky == 1) ? v1 : v2);
#pragma unroll
      for (int kx = 0; kx < 3; ++kx) {
        const int src = lane + kx - 1;
        const float s = __shfl(r, src & 63);
        v[ky * 3 + kx] = (src >= 0 && src < 64) ? s : 0.f;
      }
    }
    const float* wp = off_w + c * 9;   // uniform address
#pragma unroll
    for (int co = 0; co < 18; ++co) {
      const float* w = wp + co * 2880; // off_w[co][c][t], 9 consecutive floats
#pragma unroll
      for (int t = 0; t < 9; ++t) acc[co] += v[t] * w[t];
    }
  }

  __shared__ float red[4][18][64];
#pragma unroll
  for (int co = 0; co < 18; ++co) red[wave][co][lane] = acc[co];
  __syncthreads();
  for (int o = tid; o < 18 * 64; o += 256) {
    const int co = o >> 6, wo = o & 63;
    const float s = red[0][co][wo] + red[1][co][wo] + red[2][co][wo] +
                    red[3][co][wo] + off_b[co];
    offs[((n * 18 + co) << 12) + (ho << 6) + wo] = s;
  }
}

// ---------------------------------------------------------------------------
// K2: mask deform conv (non-modulated) on depth + sigmoid.
// grid=(4*64) blocks (n,ho), 256 threads = 4 waves x 64 lanes (lane=wo).
// Wave w handles depth channels [16w,16w+16). Bilinear params precomputed
// per thread with validity folded into the 4 corner weights (branch-free).
// ---------------------------------------------------------------------------
__global__ __launch_bounds__(256) void k_mask_conv(
    const float* __restrict__ depth, const float* __restrict__ offs,
    const float* __restrict__ mask_w, const float* __restrict__ mask_b,
    float* __restrict__ mask)
{
  const int n  = blockIdx.x >> 6;
  const int ho = blockIdx.x & 63;
  const int tid  = threadIdx.x;
  const int lane = tid & 63;          // wo
  const int wave = tid >> 6;
  const int wo = lane;

  // per-tap sampling params
  int i00[9], i01[9], i10[9], i11[9];
  float cw00[9], cw01[9], cw10[9], cw11[9];
  const float* op = offs + ((n * 18) << 12) + (ho << 6) + wo;
#pragma unroll
  for (int k = 0; k < 9; ++k) {
    const float dy = op[(2 * k) << 12];
    const float dx = op[(2 * k + 1) << 12];
    const float yy = (float)(ho - 1 + k / 3) + dy;
    const float xx = (float)(wo - 1 + k % 3) + dx;
    const float y0f = floorf(yy), x0f = floorf(xx);
    const float ly = yy - y0f, lx = xx - x0f;
    const int y0 = (int)y0f, x0 = (int)x0f;
    const int y0c = min(max(y0, 0), 63),     x0c = min(max(x0, 0), 63);
    const int y1c = min(max(y0 + 1, 0), 63), x1c = min(max(x0 + 1, 0), 63);
    const float fy0 = (y0 >= 0 && y0 < 64) ? 1.f : 0.f;
    const float fy1 = (y0 >= -1 && y0 < 63) ? 1.f : 0.f;
    const float fx0 = (x0 >= 0 && x0 < 64) ? 1.f : 0.f;
    const float fx1 = (x0 >= -1 && x0 < 63) ? 1.f : 0.f;
    i00[k] = (y0c << 6) + x0c;  i01[k] = (y0c << 6) + x1c;
    i10[k] = (y1c << 6) + x0c;  i11[k] = (y1c << 6) + x1c;
    cw00[k] = (1.f - ly) * (1.f - lx) * fy0 * fx0;
    cw01[k] = (1.f - ly) * lx * fy0 * fx1;
    cw10[k] = ly * (1.f - lx) * fy1 * fx0;
    cw11[k] = ly * lx * fy1 * fx1;
  }

  float acc[9];
#pragma unroll
  for (int i = 0; i < 9; ++i) acc[i] = 0.f;

  const int cbase = __builtin_amdgcn_readfirstlane(wave * 16);
  for (int cc = 0; cc < 16; ++cc) {
    const int c = cbase + cc;
    const float* p = depth + (((n << 6) + c) << 12);
    float val[9];
#pragma unroll
    for (int k = 0; k < 9; ++k) {
      val[k] = p[i00[k]] * cw00[k] + p[i01[k]] * cw01[k] +
               p[i10[k]] * cw10[k] + p[i11[k]] * cw11[k];
    }
    const float* wp = mask_w + c * 9;   // uniform
#pragma unroll
    for (int co = 0; co < 9; ++co) {
#pragma unroll
      for (int k = 0; k < 9; ++k) acc[co] += val[k] * wp[co * 576 + k];
    }
  }

  __shared__ float red[4][9][64];
#pragma unroll
  for (int co = 0; co < 9; ++co) red[wave][co][lane] = acc[co];
  __syncthreads();
  for (int o = tid; o < 9 * 64; o += 256) {
    const int co = o >> 6, w2 = o & 63;
    const float s = red[0][co][w2] + red[1][co][w2] + red[2][co][w2] +
                    red[3][co][w2] + mask_b[co];
    mask[((n * 9 + co) << 12) + (ho << 6) + w2] = 1.f / (1.f + expf(-s));
  }
}

// ---------------------------------------------------------------------------
// K3: main modulated deformable conv as fused im2col-GEMM.
// Per batch: C[256 x 4096] = W[256 x 2304] * cols[2304 x 4096] + bias.
// Block tile 128co x 128px, 256 threads, 8x8 microtile (ty=co, tx=px).
// K-chunks of 16 staged in LDS; cols sampled on the fly using per-block
// precomputed clamped indices + validity*mask-folded bilinear weights.
// ---------------------------------------------------------------------------
#define TK 16
__global__ __launch_bounds__(256) void k_deform_gemm(
    const float* __restrict__ x, const float* __restrict__ offs,
    const float* __restrict__ mask, const float* __restrict__ weight,
    const float* __restrict__ bias, float* __restrict__ out)
{
  __shared__ float As[TK][132];     // [kk][co], padded stride vs bank conflicts
  __shared__ float Bs[TK][128];     // [kk][px]
  __shared__ float spw0[128 * 9], spw1[128 * 9], spw2[128 * 9], spw3[128 * 9];
  __shared__ int   spi[128 * 9];    // packed clamped corner coords

  const int n   = blockIdx.z;
  const int co0 = blockIdx.y << 7;
  const int px0 = blockIdx.x << 7;
  const int tid = threadIdx.x;
  const int tx = tid & 15;          // pixel group
  const int ty = tid >> 4;          // co group

  // phase 0: sampling params for 128 pixels x 9 taps
  for (int i = tid; i < 128 * 9; i += 256) {
    const int pl = i / 9, k = i - 9 * pl;
    const int px = px0 + pl;
    const int ho = px >> 6, wo = px & 63;
    const float* op = offs + ((n * 18) << 12) + px;
    const float dy = op[(2 * k) << 12];
    const float dx = op[(2 * k + 1) << 12];
    const float m  = mask[((n * 9 + k) << 12) + px];
    const float yy = (float)(ho - 1 + k / 3) + dy;
    const float xx = (float)(wo - 1 + k % 3) + dx;
    const float y0f = floorf(yy), x0f = floorf(xx);
    const float ly = yy - y0f, lx = xx - x0f;
    const int y0 = (int)y0f, x0 = (int)x0f;
    const int y0c = min(max(y0, 0), 63),     x0c = min(max(x0, 0), 63);
    const int y1c = min(max(y0 + 1, 0), 63), x1c = min(max(x0 + 1, 0), 63);
    const float fy0 = (y0 >= 0 && y0 < 64) ? 1.f : 0.f;
    const float fy1 = (y0 >= -1 && y0 < 63) ? 1.f : 0.f;
    const float fx0 = (x0 >= 0 && x0 < 64) ? 1.f : 0.f;
    const float fx1 = (x0 >= -1 && x0 < 63) ? 1.f : 0.f;
    spw0[i] = (1.f - ly) * (1.f - lx) * fy0 * fx0 * m;
    spw1[i] = (1.f - ly) * lx * fy0 * fx1 * m;
    spw2[i] = ly * (1.f - lx) * fy1 * fx0 * m;
    spw3[i] = ly * lx * fy1 * fx1 * m;
    spi[i] = y0c | (x0c << 6) | (y1c << 12) | (x1c << 18);
  }

  float acc[8][8];
#pragma unroll
  for (int i = 0; i < 8; ++i)
#pragma unroll
    for (int j = 0; j < 8; ++j) acc[i][j] = 0.f;

  __syncthreads();

  for (int kc = 0; kc < 2304; kc += TK) {
    // stage A: weight[co0+0..127][kc..kc+15] -> As[kk][co] (coalesced 16B loads)
#pragma unroll
    for (int r = 0; r < 2; ++r) {
      const int i = r * 256 + tid;          // 0..511
      const int co_l = i >> 2;
      const int kk4  = (i & 3) << 2;
      const float4 wv = *(const float4*)(weight + (co0 + co_l) * 2304 + kc + kk4);
      As[kk4 + 0][co_l] = wv.x;
      As[kk4 + 1][co_l] = wv.y;
      As[kk4 + 2][co_l] = wv.z;
      As[kk4 + 3][co_l] = wv.w;
    }
    // stage B: sample cols[kc+kk][px0+pl] -> Bs[kk][pl]
#pragma unroll
    for (int r = 0; r < 8; ++r) {
      const int i = r * 256 + tid;          // 0..2047
      const int kk_l = i >> 7;
      const int pl   = i & 127;
      const int kkg = kc + kk_l;
      const unsigned c = (unsigned)kkg / 9u;
      const int kt = kkg - 9 * (int)c;
      const int sp = pl * 9 + kt;
      const int pk = spi[sp];
      const int y0c = pk & 63, x0c = (pk >> 6) & 63;
      const int y1c = (pk >> 12) & 63, x1c = (pk >> 18) & 63;
      const float* p = x + (((n << 8) + (int)c) << 12);
      const float v = p[(y0c << 6) + x0c] * spw0[sp] +
                      p[(y0c << 6) + x1c] * spw1[sp] +
                      p[(y1c << 6) + x0c] * spw2[sp] +
                      p[(y1c << 6) + x1c] * spw3[sp];
      Bs[kk_l][pl] = v;
    }
    __syncthreads();

    float a[8], b[8];
#pragma unroll
    for (int kk = 0; kk < TK; ++kk) {
      *(float4*)&a[0] = *(const float4*)&As[kk][ty * 8];
      *(float4*)&a[4] = *(const float4*)&As[kk][ty * 8 + 4];
      *(float4*)&b[0] = *(const float4*)&Bs[kk][tx * 8];
      *(float4*)&b[4] = *(const float4*)&Bs[kk][tx * 8 + 4];
#pragma unroll
      for (int i = 0; i < 8; ++i)
#pragma unroll
        for (int j = 0; j < 8; ++j) acc[i][j] += a[i] * b[j];
    }
    __syncthreads();
  }

  // epilogue: += bias, store 8x8 with float4
#pragma unroll
  for (int i = 0; i < 8; ++i) {
    const int co = co0 + ty * 8 + i;
    const float bv = bias[co];
    float* o = out + (((n << 8) + co) << 12) + px0 + tx * 8;
    float4 s0, s1;
    s0.x = acc[i][0] + bv; s0.y = acc[i][1] + bv;
    s0.z = acc[i][2] + bv; s0.w = acc[i][3] + bv;
    s1.x = acc[i][4] + bv; s1.y = acc[i][5] + bv;
    s1.z = acc[i][6] + bv; s1.w = acc[i][7] + bv;
    *(float4*)(o + 0) = s0;
    *(float4*)(o + 4) = s1;
  }
}

// ---------------------------------------------------------------------------
extern "C" void kernel_launch(void* const* d_in, const int* in_sizes, int n_in,
                              void* d_out, int out_size, void* d_ws, size_t ws_size,
                              hipStream_t stream) {
  const float* x      = (const float*)d_in[0];
  const float* depth  = (const float*)d_in[1];
  const float* weight = (const float*)d_in[2];
  const float* bias   = (const float*)d_in[3];
  const float* off_w  = (const float*)d_in[4];
  const float* off_b  = (const float*)d_in[5];
  const float* mask_w = (const float*)d_in[6];
  const float* mask_b = (const float*)d_in[7];
  float* out = (float*)d_out;

  float* offs = (float*)d_ws;            // 4*18*4096 = 294912 floats
  float* mask = offs + 4 * 18 * HW;      // 4*9*4096  = 147456 floats

  k_offset_conv<<<dim3(256), dim3(256), 0, stream>>>(x, depth, off_w, off_b, offs);
  k_mask_conv<<<dim3(256), dim3(256), 0, stream>>>(depth, offs, mask_w, mask_b, mask);
  k_deform_gemm<<<dim3(32, 2, 4), dim3(256), 0, stream>>>(x, offs, mask, weight,
                                                          bias, out);
}

// Round 3
// 467.620 us; speedup vs baseline: 1.6584x; 1.6584x over previous
//
#include <hip/hip_runtime.h>

// DepthDeformConvPack on MI355X — round 3: round-2 bf16-MFMA GEMM + the
// missing __syncthreads() between the sampling-param phase and the priming
// sample(0,0) (cross-wave LDS race corrupted K-chunk 0 -> absmax 1.04).
//
// Stage 0: weight fp32 -> bf16, K reordered tap-major (k' = tap*256 + c)
// Stage 1: offset = conv3x3(cat(x,depth))         [4,18,64,64]
// Stage 2: mask = sigmoid(deform_conv(depth))     [4,9,64,64]
// Stage 3: out = modulated deform conv, MFMA GEMM M=256 N=16384 K=2304

typedef __bf16 bf16x8 __attribute__((ext_vector_type(8)));
typedef float f32x4 __attribute__((ext_vector_type(4)));

__device__ __forceinline__ unsigned short f2bf(float f) {
  unsigned b = __float_as_uint(f);
  return (unsigned short)((b + 0x7fffu + ((b >> 16) & 1u)) >> 16);
}

// ---------------------------------------------------------------------------
// K0: weight[co][c][tap] fp32 -> wbf[co][tap*256 + c] bf16
// ---------------------------------------------------------------------------
__global__ __launch_bounds__(256) void k_prep_weight(
    const float* __restrict__ w, unsigned short* __restrict__ wbf)
{
  const int tap = blockIdx.x;   // 0..8
  const int co  = blockIdx.y;   // 0..255
  const int c   = threadIdx.x;  // 0..255
  wbf[co * 2304 + tap * 256 + c] = f2bf(w[(co * 256 + c) * 9 + tap]);
}

// ---------------------------------------------------------------------------
// K1: offset conv. grid = 4 ch-segments x (n,ho)=256 -> 1024 blocks, 256 thr.
// ---------------------------------------------------------------------------
__global__ __launch_bounds__(256) void k_offset_conv(
    const float* __restrict__ x, const float* __restrict__ depth,
    const float* __restrict__ off_w, const float* __restrict__ off_b,
    float* __restrict__ offs)
{
  const int seg = blockIdx.x >> 8;        // 0..3
  const int nh  = blockIdx.x & 255;
  const int n = nh >> 6, ho = nh & 63;
  const int tid = threadIdx.x;
  const int lane = tid & 63;              // == wo
  const int wave = tid >> 6;

  float acc[18];
#pragma unroll
  for (int i = 0; i < 18; ++i) acc[i] = 0.f;

  const int c0 = __builtin_amdgcn_readfirstlane(seg * 80 + wave * 20);

  for (int ci = 0; ci < 20; ++ci) {
    const int c = c0 + ci;
    const float* p = (c < 256) ? (x + (((n << 8) + c) << 12))
                               : (depth + (((n << 6) + (c - 256)) << 12));
    const float v0 = (ho > 0)  ? p[((ho - 1) << 6) + lane] : 0.f;
    const float v1 =             p[( ho      << 6) + lane];
    const float v2 = (ho < 63) ? p[((ho + 1) << 6) + lane] : 0.f;

    float v[9];
#pragma unroll
    for (int ky = 0; ky < 3; ++ky) {
      const float r = (ky == 0) ? v0 : ((ky == 1) ? v1 : v2);
#pragma unroll
      for (int kx = 0; kx < 3; ++kx) {
        const int src = lane + kx - 1;
        const float s = __shfl(r, src & 63);
        v[ky * 3 + kx] = (src >= 0 && src < 64) ? s : 0.f;
      }
    }
    const float* wp = off_w + c * 9;   // wave-uniform address
#pragma unroll
    for (int co = 0; co < 18; ++co) {
      const float* w = wp + co * 2880;
#pragma unroll
      for (int t = 0; t < 9; ++t) acc[co] += v[t] * w[t];
    }
  }

  __shared__ float red[4][18][64];
#pragma unroll
  for (int co = 0; co < 18; ++co) red[wave][co][lane] = acc[co];
  __syncthreads();
  for (int o = tid; o < 18 * 64; o += 256) {
    const int co = o >> 6, wo = o & 63;
    float s = red[0][co][wo] + red[1][co][wo] + red[2][co][wo] + red[3][co][wo];
    if (seg == 0) s += off_b[co];
    atomicAdd(&offs[((n * 18 + co) << 12) + (ho << 6) + wo], s);
  }
}

// ---------------------------------------------------------------------------
// K2: mask deform conv on depth + sigmoid. 256 blocks (n,ho), 512 thr = 8 waves.
// ---------------------------------------------------------------------------
__global__ __launch_bounds__(512) void k_mask_conv(
    const float* __restrict__ depth, const float* __restrict__ offs,
    const float* __restrict__ mask_w, const float* __restrict__ mask_b,
    float* __restrict__ mask)
{
  const int n  = blockIdx.x >> 6;
  const int ho = blockIdx.x & 63;
  const int tid  = threadIdx.x;
  const int lane = tid & 63;          // wo
  const int wave = tid >> 6;          // 0..7
  const int wo = lane;

  int i00[9], i01[9], i10[9], i11[9];
  float cw00[9], cw01[9], cw10[9], cw11[9];
  const float* op = offs + ((n * 18) << 12) + (ho << 6) + wo;
#pragma unroll
  for (int k = 0; k < 9; ++k) {
    const float dy = op[(2 * k) << 12];
    const float dx = op[(2 * k + 1) << 12];
    const float yy = (float)(ho - 1 + k / 3) + dy;
    const float xx = (float)(wo - 1 + k % 3) + dx;
    const float y0f = floorf(yy), x0f = floorf(xx);
    const float ly = yy - y0f, lx = xx - x0f;
    const int y0 = (int)y0f, x0 = (int)x0f;
    const int y0c = min(max(y0, 0), 63),     x0c = min(max(x0, 0), 63);
    const int y1c = min(max(y0 + 1, 0), 63), x1c = min(max(x0 + 1, 0), 63);
    const float fy0 = (y0 >= 0 && y0 < 64) ? 1.f : 0.f;
    const float fy1 = (y0 >= -1 && y0 < 63) ? 1.f : 0.f;
    const float fx0 = (x0 >= 0 && x0 < 64) ? 1.f : 0.f;
    const float fx1 = (x0 >= -1 && x0 < 63) ? 1.f : 0.f;
    i00[k] = (y0c << 6) + x0c;  i01[k] = (y0c << 6) + x1c;
    i10[k] = (y1c << 6) + x0c;  i11[k] = (y1c << 6) + x1c;
    cw00[k] = (1.f - ly) * (1.f - lx) * fy0 * fx0;
    cw01[k] = (1.f - ly) * lx * fy0 * fx1;
    cw10[k] = ly * (1.f - lx) * fy1 * fx0;
    cw11[k] = ly * lx * fy1 * fx1;
  }

  float acc[9];
#pragma unroll
  for (int i = 0; i < 9; ++i) acc[i] = 0.f;

  const int cbase = __builtin_amdgcn_readfirstlane(wave * 8);
  for (int cc = 0; cc < 8; ++cc) {
    const int c = cbase + cc;
    const float* p = depth + (((n << 6) + c) << 12);
    float val[9];
#pragma unroll
    for (int k = 0; k < 9; ++k) {
      val[k] = p[i00[k]] * cw00[k] + p[i01[k]] * cw01[k] +
               p[i10[k]] * cw10[k] + p[i11[k]] * cw11[k];
    }
    const float* wp = mask_w + c * 9;
#pragma unroll
    for (int co = 0; co < 9; ++co) {
#pragma unroll
      for (int k = 0; k < 9; ++k) acc[co] += val[k] * wp[co * 576 + k];
    }
  }

  __shared__ float red[8][9][64];
#pragma unroll
  for (int co = 0; co < 9; ++co) red[wave][co][lane] = acc[co];
  __syncthreads();
  for (int o = tid; o < 9 * 64; o += 512) {
    const int co = o >> 6, w2 = o & 63;
    float s = mask_b[co];
#pragma unroll
    for (int w = 0; w < 8; ++w) s += red[w][co][w2];
    mask[((n * 9 + co) << 12) + (ho << 6) + w2] = 1.f / (1.f + expf(-s));
  }
}

// ---------------------------------------------------------------------------
// K3: main modulated deform conv, bf16 MFMA GEMM.
// C[256co x 16384px] = Wbf[256 x 2304] * cols[2304 x px] (tap-major K order).
// Block: BN=64 px, BM=256 (all co), BK=64, 512 threads = 8 waves.
// ---------------------------------------------------------------------------
__global__ __launch_bounds__(512, 2) void k_deform_gemm(
    const float* __restrict__ x, const float* __restrict__ offs,
    const float* __restrict__ mask, const unsigned short* __restrict__ wbf,
    const float* __restrict__ bias, float* __restrict__ out)
{
  __shared__ __align__(16) unsigned short Bs[2][64][72];  // [buf][px][k], pad 72
  __shared__ int   pidx[576 * 2];   // packed corner indices (2x2 ushorts)
  __shared__ float pw[576 * 4];     // bilinear weights * validity * mask

  const int tid = threadIdx.x;
  const int px0 = blockIdx.x << 6;        // 0..16383
  const int n   = px0 >> 12;
  const int pxb = px0 & 4095;             // px base within batch

  // phase 0: sampling params for 64 px x 9 taps
  for (int e = tid; e < 576; e += 512) {
    const int pl = e / 9, tap = e - 9 * pl;
    const int pxg = pxb + pl;
    const int ho = pxg >> 6, wo = pxg & 63;
    const float dy = offs[((n * 18 + 2 * tap) << 12) + pxg];
    const float dx = offs[((n * 18 + 2 * tap + 1) << 12) + pxg];
    const float m  = mask[((n * 9 + tap) << 12) + pxg];
    const float yy = (float)(ho - 1 + tap / 3) + dy;
    const float xx = (float)(wo - 1 + tap % 3) + dx;
    const float y0f = floorf(yy), x0f = floorf(xx);
    const float ly = yy - y0f, lx = xx - x0f;
    const int y0 = (int)y0f, x0 = (int)x0f;
    const int y0c = min(max(y0, 0), 63),     x0c = min(max(x0, 0), 63);
    const int y1c = min(max(y0 + 1, 0), 63), x1c = min(max(x0 + 1, 0), 63);
    const float fy0 = (y0 >= 0 && y0 < 64) ? 1.f : 0.f;
    const float fy1 = (y0 >= -1 && y0 < 63) ? 1.f : 0.f;
    const float fx0 = (x0 >= 0 && x0 < 64) ? 1.f : 0.f;
    const float fx1 = (x0 >= -1 && x0 < 63) ? 1.f : 0.f;
    pidx[2 * e]     = ((y0c << 6) + x0c) | (((y0c << 6) + x1c) << 16);
    pidx[2 * e + 1] = ((y1c << 6) + x0c) | (((y1c << 6) + x1c) << 16);
    pw[4 * e + 0] = (1.f - ly) * (1.f - lx) * fy0 * fx0 * m;
    pw[4 * e + 1] = (1.f - ly) * lx * fy0 * fx1 * m;
    pw[4 * e + 2] = ly * (1.f - lx) * fy1 * fx0 * m;
    pw[4 * e + 3] = ly * lx * fy1 * fx1 * m;
  }
  // REQUIRED: sample() below reads pidx/pw written by OTHER waves.
  __syncthreads();

  const int pxl = tid & 63;
  const int oct = tid >> 6;               // 0..7; also the wave id
  const float* xn = x + ((long)(n << 8) << 12);

  auto sample = [&](int kc, int buf) {
    const int kk0 = kc + (oct << 3);      // global k' of this octet
    const int tap = kk0 >> 8;
    const int c0  = kk0 & 255;
    const int e = pxl * 9 + tap;
    const int pa = pidx[2 * e], pb = pidx[2 * e + 1];
    const int i00 = pa & 0xffff, i01 = pa >> 16;
    const int i10 = pb & 0xffff, i11 = pb >> 16;
    const float w00 = pw[4 * e], w01 = pw[4 * e + 1];
    const float w10 = pw[4 * e + 2], w11 = pw[4 * e + 3];
    const float* p = xn + (c0 << 12);
    __align__(16) unsigned short v[8];
#pragma unroll
    for (int j = 0; j < 8; ++j) {
      const float* q = p + (j << 12);
      v[j] = f2bf(q[i00] * w00 + q[i01] * w01 + q[i10] * w10 + q[i11] * w11);
    }
    *(int4*)&Bs[buf][pxl][oct << 3] = *(const int4*)v;
  };

  f32x4 acc[2][4];
#pragma unroll
  for (int mt = 0; mt < 2; ++mt)
#pragma unroll
    for (int nt = 0; nt < 4; ++nt)
#pragma unroll
      for (int r = 0; r < 4; ++r) acc[mt][nt][r] = 0.f;

  sample(0, 0);
  __syncthreads();

  const int wv   = oct;
  const int lane = tid & 63;
  const int mrow = lane & 15;
  const int koct = lane >> 4;             // 0..3 -> k-subgroup of 8

  for (int ic = 0; ic < 36; ++ic) {
    const int kc = ic << 6;
    // A fragment prefetch (global, L2-hot) — issue before sampling
    bf16x8 af[2][2];
#pragma unroll
    for (int mt = 0; mt < 2; ++mt)
#pragma unroll
      for (int ks = 0; ks < 2; ++ks) {
        const int row = (wv << 5) + (mt << 4) + mrow;
        const int col = kc + (ks << 5) + (koct << 3);
        af[mt][ks] = *(const bf16x8*)(wbf + row * 2304 + col);
      }

    if (ic + 1 < 36) sample((ic + 1) << 6, (ic + 1) & 1);

    const int buf = ic & 1;
#pragma unroll
    for (int ks = 0; ks < 2; ++ks)
#pragma unroll
      for (int nt = 0; nt < 4; ++nt) {
        const bf16x8 bfr =
            *(const bf16x8*)&Bs[buf][(nt << 4) + mrow][(ks << 5) + (koct << 3)];
        acc[0][nt] = __builtin_amdgcn_mfma_f32_16x16x32_bf16(af[0][ks], bfr,
                                                             acc[0][nt], 0, 0, 0);
        acc[1][nt] = __builtin_amdgcn_mfma_f32_16x16x32_bf16(af[1][ks], bfr,
                                                             acc[1][nt], 0, 0, 0);
      }
    __syncthreads();
  }

  // epilogue: C/D layout col=lane&15 (px), row=(lane>>4)*4+r (co)
#pragma unroll
  for (int mt = 0; mt < 2; ++mt)
#pragma unroll
    for (int nt = 0; nt < 4; ++nt)
#pragma unroll
      for (int r = 0; r < 4; ++r) {
        const int co = (wv << 5) + (mt << 4) + ((lane >> 4) << 2) + r;
        const int pxg = pxb + (nt << 4) + (lane & 15);
        out[(((n << 8) + co) << 12) + pxg] = acc[mt][nt][r] + bias[co];
      }
}

// ---------------------------------------------------------------------------
extern "C" void kernel_launch(void* const* d_in, const int* in_sizes, int n_in,
                              void* d_out, int out_size, void* d_ws, size_t ws_size,
                              hipStream_t stream) {
  const float* x      = (const float*)d_in[0];
  const float* depth  = (const float*)d_in[1];
  const float* weight = (const float*)d_in[2];
  const float* bias   = (const float*)d_in[3];
  const float* off_w  = (const float*)d_in[4];
  const float* off_b  = (const float*)d_in[5];
  const float* mask_w = (const float*)d_in[6];
  const float* mask_b = (const float*)d_in[7];
  float* out = (float*)d_out;

  float* offs = (float*)d_ws;                       // 294912 floats
  float* mask = offs + 294912;                      // 147456 floats
  unsigned short* wbf = (unsigned short*)(mask + 147456);  // 589824 bf16

  hipMemsetAsync(offs, 0, 294912 * sizeof(float), stream);
  k_prep_weight<<<dim3(9, 256), 256, 0, stream>>>(weight, wbf);
  k_offset_conv<<<1024, 256, 0, stream>>>(x, depth, off_w, off_b, offs);
  k_mask_conv<<<256, 512, 0, stream>>>(depth, offs, mask_w, mask_b, mask);
  k_deform_gemm<<<256, 512, 0, stream>>>(x, offs, mask, wbf, bias, out);
}

// Round 4
// 281.310 us; speedup vs baseline: 2.7568x; 1.6623x over previous
//
#include <hip/hip_runtime.h>

// DepthDeformConvPack on MI355X — round 4: kill the 46x HBM over-fetch in K3.
// r3 post-mortem: FETCH_SIZE=775MB vs 16.7MB of x (tap-major K revisited each
// channel 9x; per-XCD L2 thrashed between visits). Changes:
//   (a) channel-major K (k' = c*9+tap, natural weight layout) -> each channel
//       image consumed in 9 consecutive taps, L1-resident.
//   (b) bilinear via 2x dwordx2 row-pair loads (base col bx, clamp/validity/
//       mask folded into 4 remapped weights) -> half the gather instructions.
//   (c) XCD swizzle: block b -> xcd=b&7 owns a 32-row strip of one batch
//       (strip+halo ~3.1MB < 4MB L2/XCD); param tables transposed [tap][px]
//       (tap is wave-uniform in channel-major order) -> conflict-free LDS.

typedef __bf16 bf16x8 __attribute__((ext_vector_type(8)));
typedef float f32x4 __attribute__((ext_vector_type(4)));
typedef float float2_u __attribute__((ext_vector_type(2), aligned(4)));

__device__ __forceinline__ unsigned short f2bf(float f) {
  unsigned b = __float_as_uint(f);
  return (unsigned short)((b + 0x7fffu + ((b >> 16) & 1u)) >> 16);
}

// ---------------------------------------------------------------------------
// K0: weight fp32 -> bf16, natural layout (k = c*9+tap is already channel-major)
// ---------------------------------------------------------------------------
__global__ __launch_bounds__(256) void k_prep_weight(
    const float* __restrict__ w, unsigned short* __restrict__ wbf)
{
  const int i = blockIdx.x * 256 + threadIdx.x;   // grid 2304 -> 589824
  wbf[i] = f2bf(w[i]);
}

// ---------------------------------------------------------------------------
// K1: offset conv. grid = 4 ch-segments x (n,ho)=256 -> 1024 blocks, 256 thr.
// ---------------------------------------------------------------------------
__global__ __launch_bounds__(256) void k_offset_conv(
    const float* __restrict__ x, const float* __restrict__ depth,
    const float* __restrict__ off_w, const float* __restrict__ off_b,
    float* __restrict__ offs)
{
  const int seg = blockIdx.x >> 8;        // 0..3
  const int nh  = blockIdx.x & 255;
  const int n = nh >> 6, ho = nh & 63;
  const int tid = threadIdx.x;
  const int lane = tid & 63;              // == wo
  const int wave = tid >> 6;

  float acc[18];
#pragma unroll
  for (int i = 0; i < 18; ++i) acc[i] = 0.f;

  const int c0 = __builtin_amdgcn_readfirstlane(seg * 80 + wave * 20);

  for (int ci = 0; ci < 20; ++ci) {
    const int c = c0 + ci;
    const float* p = (c < 256) ? (x + (((n << 8) + c) << 12))
                               : (depth + (((n << 6) + (c - 256)) << 12));
    const float v0 = (ho > 0)  ? p[((ho - 1) << 6) + lane] : 0.f;
    const float v1 =             p[( ho      << 6) + lane];
    const float v2 = (ho < 63) ? p[((ho + 1) << 6) + lane] : 0.f;

    float v[9];
#pragma unroll
    for (int ky = 0; ky < 3; ++ky) {
      const float r = (ky == 0) ? v0 : ((ky == 1) ? v1 : v2);
#pragma unroll
      for (int kx = 0; kx < 3; ++kx) {
        const int src = lane + kx - 1;
        const float s = __shfl(r, src & 63);
        v[ky * 3 + kx] = (src >= 0 && src < 64) ? s : 0.f;
      }
    }
    const float* wp = off_w + c * 9;   // wave-uniform address
#pragma unroll
    for (int co = 0; co < 18; ++co) {
      const float* w = wp + co * 2880;
#pragma unroll
      for (int t = 0; t < 9; ++t) acc[co] += v[t] * w[t];
    }
  }

  __shared__ float red[4][18][64];
#pragma unroll
  for (int co = 0; co < 18; ++co) red[wave][co][lane] = acc[co];
  __syncthreads();
  for (int o = tid; o < 18 * 64; o += 256) {
    const int co = o >> 6, wo = o & 63;
    float s = red[0][co][wo] + red[1][co][wo] + red[2][co][wo] + red[3][co][wo];
    if (seg == 0) s += off_b[co];
    atomicAdd(&offs[((n * 18 + co) << 12) + (ho << 6) + wo], s);
  }
}

// ---------------------------------------------------------------------------
// K2: mask deform conv on depth + sigmoid. 256 blocks (n,ho), 512 thr = 8 waves.
// ---------------------------------------------------------------------------
__global__ __launch_bounds__(512) void k_mask_conv(
    const float* __restrict__ depth, const float* __restrict__ offs,
    const float* __restrict__ mask_w, const float* __restrict__ mask_b,
    float* __restrict__ mask)
{
  const int n  = blockIdx.x >> 6;
  const int ho = blockIdx.x & 63;
  const int tid  = threadIdx.x;
  const int lane = tid & 63;          // wo
  const int wave = tid >> 6;          // 0..7
  const int wo = lane;

  int i00[9], i01[9], i10[9], i11[9];
  float cw00[9], cw01[9], cw10[9], cw11[9];
  const float* op = offs + ((n * 18) << 12) + (ho << 6) + wo;
#pragma unroll
  for (int k = 0; k < 9; ++k) {
    const float dy = op[(2 * k) << 12];
    const float dx = op[(2 * k + 1) << 12];
    const float yy = (float)(ho - 1 + k / 3) + dy;
    const float xx = (float)(wo - 1 + k % 3) + dx;
    const float y0f = floorf(yy), x0f = floorf(xx);
    const float ly = yy - y0f, lx = xx - x0f;
    const int y0 = (int)y0f, x0 = (int)x0f;
    const int y0c = min(max(y0, 0), 63),     x0c = min(max(x0, 0), 63);
    const int y1c = min(max(y0 + 1, 0), 63), x1c = min(max(x0 + 1, 0), 63);
    const float fy0 = (y0 >= 0 && y0 < 64) ? 1.f : 0.f;
    const float fy1 = (y0 >= -1 && y0 < 63) ? 1.f : 0.f;
    const float fx0 = (x0 >= 0 && x0 < 64) ? 1.f : 0.f;
    const float fx1 = (x0 >= -1 && x0 < 63) ? 1.f : 0.f;
    i00[k] = (y0c << 6) + x0c;  i01[k] = (y0c << 6) + x1c;
    i10[k] = (y1c << 6) + x0c;  i11[k] = (y1c << 6) + x1c;
    cw00[k] = (1.f - ly) * (1.f - lx) * fy0 * fx0;
    cw01[k] = (1.f - ly) * lx * fy0 * fx1;
    cw10[k] = ly * (1.f - lx) * fy1 * fx0;
    cw11[k] = ly * lx * fy1 * fx1;
  }

  float acc[9];
#pragma unroll
  for (int i = 0; i < 9; ++i) acc[i] = 0.f;

  const int cbase = __builtin_amdgcn_readfirstlane(wave * 8);
  for (int cc = 0; cc < 8; ++cc) {
    const int c = cbase + cc;
    const float* p = depth + (((n << 6) + c) << 12);
    float val[9];
#pragma unroll
    for (int k = 0; k < 9; ++k) {
      val[k] = p[i00[k]] * cw00[k] + p[i01[k]] * cw01[k] +
               p[i10[k]] * cw10[k] + p[i11[k]] * cw11[k];
    }
    const float* wp = mask_w + c * 9;
#pragma unroll
    for (int co = 0; co < 9; ++co) {
#pragma unroll
      for (int k = 0; k < 9; ++k) acc[co] += val[k] * wp[co * 576 + k];
    }
  }

  __shared__ float red[8][9][64];
#pragma unroll
  for (int co = 0; co < 9; ++co) red[wave][co][lane] = acc[co];
  __syncthreads();
  for (int o = tid; o < 9 * 64; o += 512) {
    const int co = o >> 6, w2 = o & 63;
    float s = mask_b[co];
#pragma unroll
    for (int w = 0; w < 8; ++w) s += red[w][co][w2];
    mask[((n * 9 + co) << 12) + (ho << 6) + w2] = 1.f / (1.f + expf(-s));
  }
}

// ---------------------------------------------------------------------------
// K3: main modulated deform conv, bf16 MFMA GEMM, channel-major K.
// C[256co x 16384px] = Wbf[256 x 2304] * cols[2304 x px], k = c*9 + tap.
// Block: BN=64 px (one output row), BM=256, BK=64, 512 threads = 8 waves.
// ---------------------------------------------------------------------------
__global__ __launch_bounds__(512, 2) void k_deform_gemm(
    const float* __restrict__ x, const float* __restrict__ offs,
    const float* __restrict__ mask, const unsigned short* __restrict__ wbf,
    const float* __restrict__ bias, float* __restrict__ out)
{
  __shared__ __align__(16) unsigned short Bs[2][64][72];  // 18432 B
  __shared__ float4 pwT[9][64];   // [tap][px] remapped weights  9216 B
  __shared__ int2   piT[9][64];   // [tap][px] byte offsets      4608 B

  const int tid = threadIdx.x;
  // XCD swizzle: b&7 = XCD; each XCD owns a 32-row strip of one batch.
  const int b    = blockIdx.x;
  const int xcd  = b & 7, slot = b >> 3;          // slot 0..31
  const int n    = xcd >> 1;
  const int ho0  = ((xcd & 1) << 5) + slot;       // 0..63
  const int pxb  = ho0 << 6;                      // px base within batch
  const int pxg0 = (n << 12) + pxb;

  // phase 0: sampling params for 64 px x 9 taps (e = tap*64 + pl)
  for (int e = tid; e < 576; e += 512) {
    const int tap = e >> 6, pl = e & 63;
    const int pxg = pxg0 + pl;
    const int wo = pl;
    const float dy = offs[((n * 18 + 2 * tap) << 12) + pxb + pl];
    const float dx = offs[((n * 18 + 2 * tap + 1) << 12) + pxb + pl];
    const float m  = mask[((n * 9 + tap) << 12) + pxb + pl];
    (void)pxg;
    const float yy = (float)(ho0 - 1 + tap / 3) + dy;
    const float xx = (float)(wo - 1 + tap % 3) + dx;
    const float y0f = floorf(yy), x0f = floorf(xx);
    const float ly = yy - y0f, lx = xx - x0f;
    const int y0 = (int)y0f, x0 = (int)x0f;
    const int y0c = min(max(y0, 0), 63);
    const int y1c = min(max(y0 + 1, 0), 63);
    const float fy0 = (y0 >= 0 && y0 < 64) ? 1.f : 0.f;
    const float fy1 = (y0 >= -1 && y0 < 63) ? 1.f : 0.f;
    // horizontal pair remap: contribution = wl*p[bx] + wr*p[bx+1], all
    // clamp/validity cases folded (bx<=62 -> pair never crosses the row).
    const int x0c = min(max(x0, 0), 63);
    const int x1c = min(max(x0 + 1, 0), 63);
    const int bx  = min(max(x0, 0), 62);
    const float vx0 = (x0 >= 0 && x0 < 64) ? 1.f : 0.f;
    const float vx1 = (x0 >= -1 && x0 < 63) ? 1.f : 0.f;
    const float wl = (1.f - lx) * vx0 * ((x0c == bx) ? 1.f : 0.f)
                   + lx * vx1 * ((x1c == bx) ? 1.f : 0.f);
    const float wr = (1.f - lx) * vx0 * ((x0c == bx + 1) ? 1.f : 0.f)
                   + lx * vx1 * ((x1c == bx + 1) ? 1.f : 0.f);
    const float a0 = (1.f - ly) * fy0 * m;
    const float a1 = ly * fy1 * m;
    pwT[tap][pl] = make_float4(wl * a0, wr * a0, wl * a1, wr * a1);
    piT[tap][pl] = make_int2((((y0c << 6) + bx) << 2), (((y1c << 6) + bx) << 2));
  }
  __syncthreads();   // sample() reads pwT/piT written by other waves

  const int pxl = tid & 63;
  const int oct = tid >> 6;               // 0..7; also the wave id
  const float* xn = x + ((long)(n << 8) << 12);

  auto sample = [&](int kc, int buf) {
    const int kk0 = kc + (oct << 3);      // first k of this octet
    int c = (int)(((unsigned)kk0 * 7282u) >> 16);   // kk0/9 (magic, k<2304)
    int tap = kk0 - 9 * c;
    const char* p = (const char*)(xn + (c << 12));
    __align__(16) unsigned short v[8];
#pragma unroll
    for (int j = 0; j < 8; ++j) {
      const float4 w = pwT[tap][pxl];
      const int2 ii  = piT[tap][pxl];
      const float2_u pa = *(const float2_u*)(p + ii.x);
      const float2_u pb = *(const float2_u*)(p + ii.y);
      v[j] = f2bf(pa.x * w.x + pa.y * w.y + pb.x * w.z + pb.y * w.w);
      if (++tap == 9) { tap = 0; p += 16384; }   // next channel image
    }
    *(int4*)&Bs[buf][pxl][oct << 3] = *(const int4*)v;
  };

  f32x4 acc[2][4];
#pragma unroll
  for (int mt = 0; mt < 2; ++mt)
#pragma unroll
    for (int nt = 0; nt < 4; ++nt)
#pragma unroll
      for (int r = 0; r < 4; ++r) acc[mt][nt][r] = 0.f;

  sample(0, 0);
  __syncthreads();

  const int wv   = oct;
  const int lane = tid & 63;
  const int mrow = lane & 15;
  const int koct = lane >> 4;             // 0..3 -> k-subgroup of 8

  for (int ic = 0; ic < 36; ++ic) {
    const int kc = ic << 6;
    // A fragment prefetch (global, L2-hot) — issue before sampling
    bf16x8 af[2][2];
#pragma unroll
    for (int mt = 0; mt < 2; ++mt)
#pragma unroll
      for (int ks = 0; ks < 2; ++ks) {
        const int row = (wv << 5) + (mt << 4) + mrow;
        const int col = kc + (ks << 5) + (koct << 3);
        af[mt][ks] = *(const bf16x8*)(wbf + row * 2304 + col);
      }

    if (ic + 1 < 36) sample((ic + 1) << 6, (ic + 1) & 1);

    const int buf = ic & 1;
#pragma unroll
    for (int ks = 0; ks < 2; ++ks)
#pragma unroll
      for (int nt = 0; nt < 4; ++nt) {
        const bf16x8 bfr =
            *(const bf16x8*)&Bs[buf][(nt << 4) + mrow][(ks << 5) + (koct << 3)];
        acc[0][nt] = __builtin_amdgcn_mfma_f32_16x16x32_bf16(af[0][ks], bfr,
                                                             acc[0][nt], 0, 0, 0);
        acc[1][nt] = __builtin_amdgcn_mfma_f32_16x16x32_bf16(af[1][ks], bfr,
                                                             acc[1][nt], 0, 0, 0);
      }
    __syncthreads();
  }

  // epilogue: C/D layout col=lane&15 (px), row=(lane>>4)*4+r (co)
#pragma unroll
  for (int mt = 0; mt < 2; ++mt)
#pragma unroll
    for (int nt = 0; nt < 4; ++nt)
#pragma unroll
      for (int r = 0; r < 4; ++r) {
        const int co = (wv << 5) + (mt << 4) + ((lane >> 4) << 2) + r;
        const int pxg = pxb + (nt << 4) + (lane & 15);
        out[(((n << 8) + co) << 12) + pxg] = acc[mt][nt][r] + bias[co];
      }
}

// ---------------------------------------------------------------------------
extern "C" void kernel_launch(void* const* d_in, const int* in_sizes, int n_in,
                              void* d_out, int out_size, void* d_ws, size_t ws_size,
                              hipStream_t stream) {
  const float* x      = (const float*)d_in[0];
  const float* depth  = (const float*)d_in[1];
  const float* weight = (const float*)d_in[2];
  const float* bias   = (const float*)d_in[3];
  const float* off_w  = (const float*)d_in[4];
  const float* off_b  = (const float*)d_in[5];
  const float* mask_w = (const float*)d_in[6];
  const float* mask_b = (const float*)d_in[7];
  float* out = (float*)d_out;

  float* offs = (float*)d_ws;                       // 294912 floats
  float* mask = offs + 294912;                      // 147456 floats
  unsigned short* wbf = (unsigned short*)(mask + 147456);  // 589824 bf16

  hipMemsetAsync(offs, 0, 294912 * sizeof(float), stream);
  k_prep_weight<<<2304, 256, 0, stream>>>(weight, wbf);
  k_offset_conv<<<1024, 256, 0, stream>>>(x, depth, off_w, off_b, offs);
  k_mask_conv<<<256, 512, 0, stream>>>(depth, offs, mask_w, mask_b, mask);
  k_deform_gemm<<<256, 512, 0, stream>>>(x, offs, mask, wbf, bias, out);
}